// Round 1
// baseline (1726.573 us; speedup 1.0000x reference)
//
#include <hip/hip_runtime.h>

#define N_NODES 50000
#define N_EDGES 800000
#define IN_DIM  512
#define HID     256
#define LAT     128
#define K_ITERS 10
#define BN_EPS  1e-5f

// ---------------- edge dtype detect / normalize ----------------
// If edge_index is int64 (little-endian, values < 2^31), every odd 32-bit word
// is 0. If int32, odd words are random indices -> virtually never all zero.
__global__ void detect_dtype_kernel(const int* __restrict__ ei32, int* __restrict__ flag)
{
    __shared__ int any;
    if (threadIdx.x == 0) any = 0;
    __syncthreads();
    int local = 0;
    for (int i = threadIdx.x; i < 4096; i += blockDim.x)
        local |= ei32[2 * i + 1];
    if (local) atomicOr(&any, 1);
    __syncthreads();
    if (threadIdx.x == 0) flag[0] = (any != 0) ? 1 : 0;   // 1 => data is int32
}

__global__ void convert_edges_kernel(const void* __restrict__ ei, const int* __restrict__ flag,
                                     int* __restrict__ srcE, int* __restrict__ dstE, int E)
{
    int e = blockIdx.x * blockDim.x + threadIdx.x;
    if (e >= E) return;
    if (*flag) {
        const int* p = (const int*)ei;
        srcE[e] = p[e];
        dstE[e] = p[E + e];
    } else {
        const long long* p = (const long long*)ei;
        srcE[e] = (int)p[e];
        dstE[e] = (int)p[E + e];
    }
}

// ---------------- CSR build ----------------
__global__ void init_cnt_kernel(int* __restrict__ cnt, int n)
{
    int i = blockIdx.x * blockDim.x + threadIdx.x;
    if (i < n) cnt[i] = 1;   // self-loop
}

__global__ void count_edges_kernel(const int* __restrict__ dstE, int* __restrict__ cnt, int E)
{
    int e = blockIdx.x * blockDim.x + threadIdx.x;
    if (e < E) atomicAdd(&cnt[dstE[e]], 1);
}

// single-block exclusive scan of cnt -> rowoff/cursor, plus dinv = rsqrt(deg)
__global__ __launch_bounds__(1024) void scan_kernel(const int* __restrict__ cnt,
                                                    int* __restrict__ rowoff,
                                                    int* __restrict__ cursor,
                                                    float* __restrict__ dinv, int n)
{
    __shared__ int s[1024];
    const int t = threadIdx.x;
    const int chunk = (n + 1023) / 1024;
    const int lo = t * chunk;
    const int hi = min(lo + chunk, n);
    int sum = 0;
    for (int i = lo; i < hi; ++i) sum += cnt[i];
    s[t] = sum;
    __syncthreads();
    for (int off = 1; off < 1024; off <<= 1) {
        int v = (t >= off) ? s[t - off] : 0;
        __syncthreads();
        s[t] += v;
        __syncthreads();
    }
    int run = s[t] - sum;   // exclusive prefix
    for (int i = lo; i < hi; ++i) {
        rowoff[i] = run;
        cursor[i] = run;
        run += cnt[i];
        dinv[i] = rsqrtf((float)cnt[i]);
    }
    if (t == 1023) rowoff[n] = s[1023];
}

__global__ void scatter_kernel(const int* __restrict__ srcE, const int* __restrict__ dstE,
                               const float* __restrict__ dinv, int* __restrict__ cursor,
                               int* __restrict__ csr_src, float* __restrict__ csr_w,
                               int E, int n)
{
    int e = blockIdx.x * blockDim.x + threadIdx.x;
    if (e >= E + n) return;
    int s, d;
    if (e < E) { s = srcE[e]; d = dstE[e]; }
    else       { s = e - E;   d = s; }
    int pos = atomicAdd(&cursor[d], 1);
    csr_src[pos] = s;
    csr_w[pos]   = dinv[s] * dinv[d];
}

// ---------------- GEMM: C = A[M,K] @ B[K,Nc], f32, 128x128 tile ----------------
// EPI = 0: plain. EPI = 1: relu(bn(C + bias)) with per-column params.
template<int EPI>
__global__ __launch_bounds__(256) void gemm_f32_128(const float* __restrict__ A,
                                                    const float* __restrict__ B,
                                                    float* __restrict__ C,
                                                    int M, int K, int Nc,
                                                    const float* __restrict__ cb,
                                                    const float* __restrict__ cg,
                                                    const float* __restrict__ cbe,
                                                    const float* __restrict__ cm,
                                                    const float* __restrict__ cv)
{
    __shared__ float As[16][128];
    __shared__ float Bs[16][128];
    const int tid = threadIdx.x;
    const int tx = tid & 15, ty = tid >> 4;
    const int rowBase = blockIdx.y * 128;
    const int colBase = blockIdx.x * 128;

    float c[8][8];
#pragma unroll
    for (int i = 0; i < 8; ++i)
#pragma unroll
        for (int j = 0; j < 8; ++j) c[i][j] = 0.f;

    const int ar = tid >> 2;        // 0..63
    const int ak = (tid & 3) * 4;   // 0,4,8,12
    const int bk = tid >> 4;        // 0..15
    const int bc = (tid & 15) * 4;  // 0..60

    for (int k0 = 0; k0 < K; k0 += 16) {
        __syncthreads();
#pragma unroll
        for (int p = 0; p < 2; ++p) {
            int r = ar + p * 64;
            int row = rowBase + r;
            float4 v = make_float4(0.f, 0.f, 0.f, 0.f);
            if (row < M) v = *(const float4*)&A[(size_t)row * K + k0 + ak];
            As[ak + 0][r] = v.x; As[ak + 1][r] = v.y;
            As[ak + 2][r] = v.z; As[ak + 3][r] = v.w;
        }
        {
            float4 v0 = *(const float4*)&B[(size_t)(k0 + bk) * Nc + colBase + bc];
            float4 v1 = *(const float4*)&B[(size_t)(k0 + bk) * Nc + colBase + 64 + bc];
            *(float4*)&Bs[bk][bc]      = v0;
            *(float4*)&Bs[bk][64 + bc] = v1;
        }
        __syncthreads();
#pragma unroll
        for (int kk = 0; kk < 16; ++kk) {
            float a[8], b[8];
            *(float4*)&a[0] = *(const float4*)&As[kk][ty * 8];
            *(float4*)&a[4] = *(const float4*)&As[kk][ty * 8 + 4];
            *(float4*)&b[0] = *(const float4*)&Bs[kk][tx * 8];
            *(float4*)&b[4] = *(const float4*)&Bs[kk][tx * 8 + 4];
#pragma unroll
            for (int i = 0; i < 8; ++i)
#pragma unroll
                for (int j = 0; j < 8; ++j)
                    c[i][j] = fmaf(a[i], b[j], c[i][j]);
        }
    }

    float epi_sc[8], epi_sh[8];
    if (EPI == 1) {
#pragma unroll
        for (int j = 0; j < 8; ++j) {
            int col = colBase + tx * 8 + j;
            float sc = cg[col] * rsqrtf(cv[col] + BN_EPS);
            epi_sc[j] = sc;
            epi_sh[j] = (cb[col] - cm[col]) * sc + cbe[col];
        }
    }

#pragma unroll
    for (int i = 0; i < 8; ++i) {
        int row = rowBase + ty * 8 + i;
        if (row < M) {
            float v[8];
#pragma unroll
            for (int j = 0; j < 8; ++j) {
                float x = c[i][j];
                if (EPI == 1) x = fmaxf(x * epi_sc[j] + epi_sh[j], 0.f);
                v[j] = x;
            }
            *(float4*)&C[(size_t)row * Nc + colBase + tx * 8]     = make_float4(v[0], v[1], v[2], v[3]);
            *(float4*)&C[(size_t)row * Nc + colBase + tx * 8 + 4] = make_float4(v[4], v[5], v[6], v[7]);
        }
    }
}

// ---------------- propagates (all 128-dim, one node per block) ----------------
__global__ void prop_plain_kernel(const float* __restrict__ hin,
                                  const int* __restrict__ rowoff,
                                  const int* __restrict__ csr_src,
                                  const float* __restrict__ csr_w,
                                  float* __restrict__ out)
{
    const int node = blockIdx.x;
    const int d = threadIdx.x;
    const int e0 = rowoff[node], e1 = rowoff[node + 1];
    float acc = 0.f;
    for (int e = e0; e < e1; ++e)
        acc = fmaf(csr_w[e], hin[(size_t)csr_src[e] * LAT + d], acc);
    out[(size_t)node * LAT + d] = acc;
}

__global__ void prop_gcn_kernel(const float* __restrict__ hin,
                                const int* __restrict__ rowoff,
                                const int* __restrict__ csr_src,
                                const float* __restrict__ csr_w,
                                const float* __restrict__ bias,
                                const float* __restrict__ gamma,
                                const float* __restrict__ beta,
                                const float* __restrict__ mean,
                                const float* __restrict__ var,
                                float* __restrict__ out)
{
    const int node = blockIdx.x;
    const int d = threadIdx.x;
    const int e0 = rowoff[node], e1 = rowoff[node + 1];
    float acc = 0.f;
    for (int e = e0; e < e1; ++e)
        acc = fmaf(csr_w[e], hin[(size_t)csr_src[e] * LAT + d], acc);
    float sc = gamma[d] * rsqrtf(var[d] + BN_EPS);
    float v = (acc + bias[d] - mean[d]) * sc + beta[d];
    out[(size_t)node * LAT + d] = fmaxf(v, 0.f);
}

template<bool ADD_Z0>
__global__ void prop_appnp_kernel(const float* __restrict__ hin,
                                  const int* __restrict__ rowoff,
                                  const int* __restrict__ csr_src,
                                  const float* __restrict__ csr_w,
                                  const float* __restrict__ h2,
                                  const float* __restrict__ z0,
                                  float* __restrict__ out)
{
    const int node = blockIdx.x;
    const int d = threadIdx.x;
    const int e0 = rowoff[node], e1 = rowoff[node + 1];
    float acc = 0.f;
    for (int e = e0; e < e1; ++e)
        acc = fmaf(csr_w[e], hin[(size_t)csr_src[e] * LAT + d], acc);
    float r = 0.9f * acc + 0.1f * h2[(size_t)node * LAT + d];
    if (ADD_Z0) r += z0[(size_t)node * LAT + d];
    out[(size_t)node * LAT + d] = r;
}

// ---------------- edge sigmoid-dot: one wave per edge ----------------
__global__ __launch_bounds__(256) void edge_dot_kernel(const float* __restrict__ z,
                                                       const int* __restrict__ srcE,
                                                       const int* __restrict__ dstE,
                                                       float* __restrict__ adj, int E)
{
    int gw   = (blockIdx.x * 256 + threadIdx.x) >> 6;
    int lane = threadIdx.x & 63;
    if (gw >= E) return;
    int r = srcE[gw], c = dstE[gw];
    float2 a = *(const float2*)&z[(size_t)r * LAT + lane * 2];
    float2 b = *(const float2*)&z[(size_t)c * LAT + lane * 2];
    float acc = a.x * b.x + a.y * b.y;
#pragma unroll
    for (int m = 32; m >= 1; m >>= 1) acc += __shfl_xor(acc, m, 64);
    if (lane == 0) adj[gw] = 1.f / (1.f + expf(-acc));
}

// ---------------- launcher ----------------
extern "C" void kernel_launch(void* const* d_in, const int* in_sizes, int n_in,
                              void* d_out, int out_size, void* d_ws, size_t ws_size,
                              hipStream_t stream)
{
    const float* x     = (const float*)d_in[0];
    const void*  ei    = d_in[1];
    const float* Wproj = (const float*)d_in[2];
    const float* W1    = (const float*)d_in[3];
    const float* b1    = (const float*)d_in[4];
    const float* g1    = (const float*)d_in[5];
    const float* be1   = (const float*)d_in[6];
    const float* m1    = (const float*)d_in[7];
    const float* v1    = (const float*)d_in[8];
    const float* W2    = (const float*)d_in[9];
    const float* b2    = (const float*)d_in[10];
    const float* g2    = (const float*)d_in[11];
    const float* be2   = (const float*)d_in[12];
    const float* m2    = (const float*)d_in[13];
    const float* v2    = (const float*)d_in[14];

    float* out_adj = (float*)d_out;
    float* out_z   = (float*)d_out + N_EDGES;

    char* w = (char*)d_ws;
    size_t off = 0;
    auto alloc = [&](size_t bytes) {
        void* p = w + off;
        off += (bytes + 255) & ~(size_t)255;
        return p;
    };
    int*   flag    = (int*)  alloc(4);
    int*   cnt     = (int*)  alloc((size_t)N_NODES * 4);
    int*   cursor  = (int*)  alloc((size_t)N_NODES * 4);
    int*   rowoff  = (int*)  alloc((size_t)(N_NODES + 1) * 4);
    float* dinv    = (float*)alloc((size_t)N_NODES * 4);
    int*   srcE    = (int*)  alloc((size_t)N_EDGES * 4);
    int*   dstE    = (int*)  alloc((size_t)N_EDGES * 4);
    int*   csr_src = (int*)  alloc((size_t)(N_EDGES + N_NODES) * 4);
    float* csr_w   = (float*)alloc((size_t)(N_EDGES + N_NODES) * 4);
    float* z0      = (float*)alloc((size_t)N_NODES * LAT * 4);
    float* p0      = (float*)alloc((size_t)N_NODES * LAT * 4);   // also t2 / pingA
    float* h1      = (float*)alloc((size_t)N_NODES * HID * 4);   // also h2 (first half) + pingB (second half)

    float* h2    = h1;                       // [N,128] first half of h1 buffer
    float* pingA = p0;
    float* pingB = h1 + (size_t)N_NODES * LAT;

    // graph preprocessing
    detect_dtype_kernel<<<1, 256, 0, stream>>>((const int*)ei, flag);
    convert_edges_kernel<<<(N_EDGES + 255) / 256, 256, 0, stream>>>(ei, flag, srcE, dstE, N_EDGES);
    init_cnt_kernel<<<(N_NODES + 255) / 256, 256, 0, stream>>>(cnt, N_NODES);
    count_edges_kernel<<<(N_EDGES + 255) / 256, 256, 0, stream>>>(dstE, cnt, N_EDGES);
    scan_kernel<<<1, 1024, 0, stream>>>(cnt, rowoff, cursor, dinv, N_NODES);
    scatter_kernel<<<(N_EDGES + N_NODES + 255) / 256, 256, 0, stream>>>(srcE, dstE, dinv, cursor,
                                                                        csr_src, csr_w, N_EDGES, N_NODES);

    const int gy = (N_NODES + 127) / 128;   // 391

    // z0 = x @ Wproj
    gemm_f32_128<0><<<dim3(LAT / 128, gy), 256, 0, stream>>>(x, Wproj, z0, N_NODES, IN_DIM, LAT,
                                                             nullptr, nullptr, nullptr, nullptr, nullptr);
    // p0 = prop(z0)       [ prop(z0 @ W1) == prop(z0) @ W1 ]
    prop_plain_kernel<<<N_NODES, LAT, 0, stream>>>(z0, rowoff, csr_src, csr_w, p0);
    // h1 = relu(bn(p0 @ W1 + b1))
    gemm_f32_128<1><<<dim3(HID / 128, gy), 256, 0, stream>>>(p0, W1, h1, N_NODES, LAT, HID,
                                                             b1, g1, be1, m1, v1);
    // t2 = h1 @ W2   (into p0 buffer)
    gemm_f32_128<0><<<dim3(LAT / 128, gy), 256, 0, stream>>>(h1, W2, p0, N_NODES, HID, LAT,
                                                             nullptr, nullptr, nullptr, nullptr, nullptr);
    // h2 = relu(bn(prop(t2) + b2))   (into h1 buffer first half)
    prop_gcn_kernel<<<N_NODES, LAT, 0, stream>>>(p0, rowoff, csr_src, csr_w,
                                                 b2, g2, be2, m2, v2, h2);

    // APPNP: h_{k+1} = 0.9 * prop(h_k) + 0.1 * h2 ; final += z0, into out_z
    const float* cur = h2;
    for (int it = 0; it < K_ITERS; ++it) {
        if (it == K_ITERS - 1) {
            prop_appnp_kernel<true><<<N_NODES, LAT, 0, stream>>>(cur, rowoff, csr_src, csr_w,
                                                                 h2, z0, out_z);
            cur = out_z;
        } else {
            float* nxt = (it & 1) ? pingB : pingA;
            prop_appnp_kernel<false><<<N_NODES, LAT, 0, stream>>>(cur, rowoff, csr_src, csr_w,
                                                                  h2, z0, nxt);
            cur = nxt;
        }
    }

    // adj = sigmoid(sum(z[row] * z[col]))
    edge_dot_kernel<<<(N_EDGES + 3) / 4, 256, 0, stream>>>(out_z, srcE, dstE, out_adj, N_EDGES);
}

// Round 2
// 1208.904 us; speedup vs baseline: 1.4282x; 1.4282x over previous
//
#include <hip/hip_runtime.h>

#define N_NODES 50000
#define N_EDGES 800000
#define IN_DIM  512
#define HID     256
#define LAT     128
#define K_ITERS 10
#define BN_EPS  1e-5f

typedef __attribute__((ext_vector_type(8))) unsigned short ushort8;

// ---------------- bf16 helpers ----------------
__device__ inline float2 bf2f2(unsigned v)
{
    float lo = __builtin_bit_cast(float, v << 16);
    float hi = __builtin_bit_cast(float, v & 0xffff0000u);
    return make_float2(lo, hi);
}
__device__ inline unsigned f2bf_bits(float f)
{
    unsigned u = __builtin_bit_cast(unsigned, f);
    return (u + 0x7fffu + ((u >> 16) & 1u)) >> 16;   // RTNE
}
__device__ inline unsigned packbf(float x, float y)
{
    return f2bf_bits(x) | (f2bf_bits(y) << 16);
}

// ---------------- edge dtype detect / normalize ----------------
__global__ void detect_dtype_kernel(const int* __restrict__ ei32, int* __restrict__ flag)
{
    __shared__ int any;
    if (threadIdx.x == 0) any = 0;
    __syncthreads();
    int local = 0;
    for (int i = threadIdx.x; i < 4096; i += blockDim.x)
        local |= ei32[2 * i + 1];
    if (local) atomicOr(&any, 1);
    __syncthreads();
    if (threadIdx.x == 0) flag[0] = (any != 0) ? 1 : 0;   // 1 => data is int32
}

__global__ void convert_edges_kernel(const void* __restrict__ ei, const int* __restrict__ flag,
                                     int* __restrict__ srcE, int* __restrict__ dstE, int E)
{
    int e = blockIdx.x * blockDim.x + threadIdx.x;
    if (e >= E) return;
    if (*flag) {
        const int* p = (const int*)ei;
        srcE[e] = p[e];
        dstE[e] = p[E + e];
    } else {
        const long long* p = (const long long*)ei;
        srcE[e] = (int)p[e];
        dstE[e] = (int)p[E + e];
    }
}

// ---------------- CSR build ----------------
__global__ void init_cnt_kernel(int* __restrict__ cnt, int n)
{
    int i = blockIdx.x * blockDim.x + threadIdx.x;
    if (i < n) cnt[i] = 1;   // self-loop
}

__global__ void count_edges_kernel(const int* __restrict__ dstE, int* __restrict__ cnt, int E)
{
    int e = blockIdx.x * blockDim.x + threadIdx.x;
    if (e < E) atomicAdd(&cnt[dstE[e]], 1);
}

__global__ __launch_bounds__(1024) void scan_kernel(const int* __restrict__ cnt,
                                                    int* __restrict__ rowoff,
                                                    int* __restrict__ cursor,
                                                    float* __restrict__ dinv, int n)
{
    __shared__ int s[1024];
    const int t = threadIdx.x;
    const int chunk = (n + 1023) / 1024;
    const int lo = t * chunk;
    const int hi = min(lo + chunk, n);
    int sum = 0;
    for (int i = lo; i < hi; ++i) sum += cnt[i];
    s[t] = sum;
    __syncthreads();
    for (int off = 1; off < 1024; off <<= 1) {
        int v = (t >= off) ? s[t - off] : 0;
        __syncthreads();
        s[t] += v;
        __syncthreads();
    }
    int run = s[t] - sum;   // exclusive prefix
    for (int i = lo; i < hi; ++i) {
        rowoff[i] = run;
        cursor[i] = run;
        run += cnt[i];
        dinv[i] = rsqrtf((float)cnt[i]);
    }
    if (t == 1023) rowoff[n] = s[1023];
}

__global__ void scatter_kernel(const int* __restrict__ srcE, const int* __restrict__ dstE,
                               const float* __restrict__ dinv, int* __restrict__ cursor,
                               int* __restrict__ csr_src, float* __restrict__ csr_w,
                               int E, int n)
{
    int e = blockIdx.x * blockDim.x + threadIdx.x;
    if (e >= E + n) return;
    int s, d;
    if (e < E) { s = srcE[e]; d = dstE[e]; }
    else       { s = e - E;   d = s; }
    int pos = atomicAdd(&cursor[d], 1);
    csr_src[pos] = s;
    csr_w[pos]   = dinv[s] * dinv[d];
}

// ---------------- GEMM: C = A[M,K] @ B[K,Nc], f32 accum, 128x128 tile -------
// EPI 0: f32 out. EPI 1: relu(bn(C+bias)) f32 out. EPI 2: bf16 out (packed).
template<int EPI>
__global__ __launch_bounds__(256) void gemm_f32_128(const float* __restrict__ A,
                                                    const float* __restrict__ B,
                                                    void* __restrict__ Cv,
                                                    int M, int K, int Nc,
                                                    const float* __restrict__ cb,
                                                    const float* __restrict__ cg,
                                                    const float* __restrict__ cbe,
                                                    const float* __restrict__ cm,
                                                    const float* __restrict__ cv)
{
    __shared__ float As[16][128];
    __shared__ float Bs[16][128];
    const int tid = threadIdx.x;
    const int tx = tid & 15, ty = tid >> 4;
    const int rowBase = blockIdx.y * 128;
    const int colBase = blockIdx.x * 128;

    float c[8][8];
#pragma unroll
    for (int i = 0; i < 8; ++i)
#pragma unroll
        for (int j = 0; j < 8; ++j) c[i][j] = 0.f;

    const int ar = tid >> 2;        // 0..63
    const int ak = (tid & 3) * 4;   // 0,4,8,12
    const int bk = tid >> 4;        // 0..15
    const int bc = (tid & 15) * 4;  // 0..60

    for (int k0 = 0; k0 < K; k0 += 16) {
        __syncthreads();
#pragma unroll
        for (int p = 0; p < 2; ++p) {
            int r = ar + p * 64;
            int row = rowBase + r;
            float4 v = make_float4(0.f, 0.f, 0.f, 0.f);
            if (row < M) v = *(const float4*)&A[(size_t)row * K + k0 + ak];
            As[ak + 0][r] = v.x; As[ak + 1][r] = v.y;
            As[ak + 2][r] = v.z; As[ak + 3][r] = v.w;
        }
        {
            float4 v0 = *(const float4*)&B[(size_t)(k0 + bk) * Nc + colBase + bc];
            float4 v1 = *(const float4*)&B[(size_t)(k0 + bk) * Nc + colBase + 64 + bc];
            *(float4*)&Bs[bk][bc]      = v0;
            *(float4*)&Bs[bk][64 + bc] = v1;
        }
        __syncthreads();
#pragma unroll
        for (int kk = 0; kk < 16; ++kk) {
            float a[8], b[8];
            *(float4*)&a[0] = *(const float4*)&As[kk][ty * 8];
            *(float4*)&a[4] = *(const float4*)&As[kk][ty * 8 + 4];
            *(float4*)&b[0] = *(const float4*)&Bs[kk][tx * 8];
            *(float4*)&b[4] = *(const float4*)&Bs[kk][tx * 8 + 4];
#pragma unroll
            for (int i = 0; i < 8; ++i)
#pragma unroll
                for (int j = 0; j < 8; ++j)
                    c[i][j] = fmaf(a[i], b[j], c[i][j]);
        }
    }

    float epi_sc[8], epi_sh[8];
    if (EPI == 1) {
#pragma unroll
        for (int j = 0; j < 8; ++j) {
            int col = colBase + tx * 8 + j;
            float sc = cg[col] * rsqrtf(cv[col] + BN_EPS);
            epi_sc[j] = sc;
            epi_sh[j] = (cb[col] - cm[col]) * sc + cbe[col];
        }
    }

#pragma unroll
    for (int i = 0; i < 8; ++i) {
        int row = rowBase + ty * 8 + i;
        if (row < M) {
            float v[8];
#pragma unroll
            for (int j = 0; j < 8; ++j) {
                float x = c[i][j];
                if (EPI == 1) x = fmaxf(x * epi_sc[j] + epi_sh[j], 0.f);
                v[j] = x;
            }
            if (EPI == 2) {
                ushort8 o;
#pragma unroll
                for (int j = 0; j < 8; ++j) o[j] = (unsigned short)f2bf_bits(v[j]);
                *(ushort8*)&((unsigned short*)Cv)[(size_t)row * Nc + colBase + tx * 8] = o;
            } else {
                float* C = (float*)Cv;
                *(float4*)&C[(size_t)row * Nc + colBase + tx * 8]     = make_float4(v[0], v[1], v[2], v[3]);
                *(float4*)&C[(size_t)row * Nc + colBase + tx * 8 + 4] = make_float4(v[4], v[5], v[6], v[7]);
            }
        }
    }
}

// ---------------- propagate, bf16 input rows, one wave per node ----------------
// lane l holds dims (2l, 2l+1) packed in one dword.
// MODE 0: out f32 (p0).  MODE 1: bn+relu -> bf16.  MODE 2: APPNP mid -> bf16.
// MODE 3: APPNP final: f32 z to outf, bf16 mirror to outh (may alias z0h).
template<int MODE>
__global__ __launch_bounds__(256) void prop_bf16(const unsigned* __restrict__ in,
                                                 const int* __restrict__ rowoff,
                                                 const int* __restrict__ csr_src,
                                                 const float* __restrict__ csr_w,
                                                 const unsigned* __restrict__ h2h,
                                                 const unsigned* __restrict__ z0h,
                                                 float* __restrict__ outf,
                                                 unsigned* outh,
                                                 const float* __restrict__ bb,
                                                 const float* __restrict__ bg,
                                                 const float* __restrict__ bbe,
                                                 const float* __restrict__ bm,
                                                 const float* __restrict__ bv)
{
    const int node = blockIdx.x * 4 + (threadIdx.x >> 6);
    const int lane = threadIdx.x & 63;
    const int e0 = rowoff[node], e1 = rowoff[node + 1];

    float2 a0 = make_float2(0.f, 0.f), a1 = make_float2(0.f, 0.f);
    int e = e0;
    for (; e + 2 <= e1; e += 2) {
        int s0 = csr_src[e], s1 = csr_src[e + 1];
        float w0 = csr_w[e],  w1 = csr_w[e + 1];
        unsigned v0 = in[(size_t)s0 * 64 + lane];
        unsigned v1 = in[(size_t)s1 * 64 + lane];
        float2 f0 = bf2f2(v0), f1 = bf2f2(v1);
        a0.x = fmaf(w0, f0.x, a0.x); a0.y = fmaf(w0, f0.y, a0.y);
        a1.x = fmaf(w1, f1.x, a1.x); a1.y = fmaf(w1, f1.y, a1.y);
    }
    if (e < e1) {
        int s0 = csr_src[e]; float w0 = csr_w[e];
        float2 f0 = bf2f2(in[(size_t)s0 * 64 + lane]);
        a0.x = fmaf(w0, f0.x, a0.x); a0.y = fmaf(w0, f0.y, a0.y);
    }
    float ax = a0.x + a1.x;
    float ay = a0.y + a1.y;

    if (MODE == 0) {
        *(float2*)&outf[(size_t)node * LAT + 2 * lane] = make_float2(ax, ay);
    } else if (MODE == 1) {
        int d0 = 2 * lane, d1 = d0 + 1;
        float sc0 = bg[d0] * rsqrtf(bv[d0] + BN_EPS);
        float sh0 = (bb[d0] - bm[d0]) * sc0 + bbe[d0];
        float sc1 = bg[d1] * rsqrtf(bv[d1] + BN_EPS);
        float sh1 = (bb[d1] - bm[d1]) * sc1 + bbe[d1];
        float r0 = fmaxf(fmaf(ax, sc0, sh0), 0.f);
        float r1 = fmaxf(fmaf(ay, sc1, sh1), 0.f);
        outh[(size_t)node * 64 + lane] = packbf(r0, r1);
    } else if (MODE == 2) {
        float2 h2v = bf2f2(h2h[(size_t)node * 64 + lane]);
        float r0 = fmaf(0.9f, ax, 0.1f * h2v.x);
        float r1 = fmaf(0.9f, ay, 0.1f * h2v.y);
        outh[(size_t)node * 64 + lane] = packbf(r0, r1);
    } else {   // MODE 3
        float2 h2v = bf2f2(h2h[(size_t)node * 64 + lane]);
        float2 z0v = bf2f2(z0h[(size_t)node * 64 + lane]);
        float r0 = fmaf(0.9f, ax, 0.1f * h2v.x) + z0v.x;
        float r1 = fmaf(0.9f, ay, 0.1f * h2v.y) + z0v.y;
        *(float2*)&outf[(size_t)node * LAT + 2 * lane] = make_float2(r0, r1);
        outh[(size_t)node * 64 + lane] = packbf(r0, r1);
    }
}

// ---------------- edge sigmoid-dot on bf16 z: one wave per edge --------------
__global__ __launch_bounds__(256) void edge_dot_bf16(const unsigned* __restrict__ zh,
                                                     const int* __restrict__ srcE,
                                                     const int* __restrict__ dstE,
                                                     float* __restrict__ adj, int E)
{
    int gw   = (blockIdx.x * 256 + threadIdx.x) >> 6;
    int lane = threadIdx.x & 63;
    if (gw >= E) return;
    int r = srcE[gw], c = dstE[gw];
    float2 a = bf2f2(zh[(size_t)r * 64 + lane]);
    float2 b = bf2f2(zh[(size_t)c * 64 + lane]);
    float acc = a.x * b.x + a.y * b.y;
#pragma unroll
    for (int m = 32; m >= 1; m >>= 1) acc += __shfl_xor(acc, m, 64);
    if (lane == 0) adj[gw] = 1.f / (1.f + expf(-acc));
}

// ---------------- launcher ----------------
extern "C" void kernel_launch(void* const* d_in, const int* in_sizes, int n_in,
                              void* d_out, int out_size, void* d_ws, size_t ws_size,
                              hipStream_t stream)
{
    const float* x     = (const float*)d_in[0];
    const void*  ei    = d_in[1];
    const float* Wproj = (const float*)d_in[2];
    const float* W1    = (const float*)d_in[3];
    const float* b1    = (const float*)d_in[4];
    const float* g1    = (const float*)d_in[5];
    const float* be1   = (const float*)d_in[6];
    const float* m1    = (const float*)d_in[7];
    const float* v1    = (const float*)d_in[8];
    const float* W2    = (const float*)d_in[9];
    const float* b2    = (const float*)d_in[10];
    const float* g2    = (const float*)d_in[11];
    const float* be2   = (const float*)d_in[12];
    const float* m2    = (const float*)d_in[13];
    const float* v2    = (const float*)d_in[14];

    float* out_adj = (float*)d_out;
    float* out_z   = (float*)d_out + N_EDGES;

    char* w = (char*)d_ws;
    size_t off = 0;
    auto alloc = [&](size_t bytes) {
        void* p = w + off;
        off += (bytes + 255) & ~(size_t)255;
        return p;
    };
    const size_t NB = (size_t)N_NODES * 64 * 4;   // one bf16 [N,128] plane = 12.8 MB

    int*      flag    = (int*)     alloc(4);
    int*      cnt     = (int*)     alloc((size_t)N_NODES * 4);
    int*      cursor  = (int*)     alloc((size_t)N_NODES * 4);
    int*      rowoff  = (int*)     alloc((size_t)(N_NODES + 1) * 4);
    float*    dinv    = (float*)   alloc((size_t)N_NODES * 4);
    int*      srcE    = (int*)     alloc((size_t)N_EDGES * 4);
    int*      dstE    = (int*)     alloc((size_t)N_EDGES * 4);
    int*      csr_src = (int*)     alloc((size_t)(N_EDGES + N_NODES) * 4);
    float*    csr_w   = (float*)   alloc((size_t)(N_EDGES + N_NODES) * 4);
    unsigned* z0h     = (unsigned*)alloc(NB);           // bf16 z0; final z mirror in-place
    char*     big0    = (char*)    alloc(2 * NB);       // p0 f32 | later t2h + pingA/pingB
    char*     big1    = (char*)    alloc(4 * NB);       // h1 f32 | later h2h

    float*    p0    = (float*)big0;
    unsigned* t2h   = (unsigned*)big0;
    unsigned* pingA = (unsigned*)big0;
    unsigned* pingB = (unsigned*)(big0 + NB);
    float*    h1    = (float*)big1;
    unsigned* h2h   = (unsigned*)big1;

    // graph preprocessing
    detect_dtype_kernel<<<1, 256, 0, stream>>>((const int*)ei, flag);
    convert_edges_kernel<<<(N_EDGES + 255) / 256, 256, 0, stream>>>(ei, flag, srcE, dstE, N_EDGES);
    init_cnt_kernel<<<(N_NODES + 255) / 256, 256, 0, stream>>>(cnt, N_NODES);
    count_edges_kernel<<<(N_EDGES + 255) / 256, 256, 0, stream>>>(dstE, cnt, N_EDGES);
    scan_kernel<<<1, 1024, 0, stream>>>(cnt, rowoff, cursor, dinv, N_NODES);
    scatter_kernel<<<(N_EDGES + N_NODES + 255) / 256, 256, 0, stream>>>(srcE, dstE, dinv, cursor,
                                                                        csr_src, csr_w, N_EDGES, N_NODES);

    const int gy = (N_NODES + 127) / 128;   // 391
    const int pgrid = N_NODES / 4;          // 12500, one wave per node

    // z0h = bf16(x @ Wproj)
    gemm_f32_128<2><<<dim3(1, gy), 256, 0, stream>>>(x, Wproj, z0h, N_NODES, IN_DIM, LAT,
                                                     nullptr, nullptr, nullptr, nullptr, nullptr);
    // p0 = prop(z0)  [f32]    ( prop(z0 @ W1) == prop(z0) @ W1 )
    prop_bf16<0><<<pgrid, 256, 0, stream>>>(z0h, rowoff, csr_src, csr_w, nullptr, nullptr,
                                            p0, nullptr, nullptr, nullptr, nullptr, nullptr, nullptr);
    // h1 = relu(bn(p0 @ W1 + b1))  [f32]
    gemm_f32_128<1><<<dim3(HID / 128, gy), 256, 0, stream>>>(p0, W1, h1, N_NODES, LAT, HID,
                                                             b1, g1, be1, m1, v1);
    // t2h = bf16(h1 @ W2)
    gemm_f32_128<2><<<dim3(1, gy), 256, 0, stream>>>(h1, W2, t2h, N_NODES, HID, LAT,
                                                     nullptr, nullptr, nullptr, nullptr, nullptr);
    // h2h = bf16(relu(bn(prop(t2) + b2)))
    prop_bf16<1><<<pgrid, 256, 0, stream>>>(t2h, rowoff, csr_src, csr_w, nullptr, nullptr,
                                            nullptr, h2h, b2, g2, be2, m2, v2);

    // APPNP: h_{k+1} = 0.9 * prop(h_k) + 0.1 * h2 ; final adds z0, writes f32 z + bf16 mirror
    const unsigned* cur = h2h;
    for (int it = 0; it < K_ITERS; ++it) {
        if (it == K_ITERS - 1) {
            prop_bf16<3><<<pgrid, 256, 0, stream>>>(cur, rowoff, csr_src, csr_w, h2h, z0h,
                                                    out_z, z0h, nullptr, nullptr, nullptr, nullptr, nullptr);
        } else {
            unsigned* nxt = (it & 1) ? pingB : pingA;
            prop_bf16<2><<<pgrid, 256, 0, stream>>>(cur, rowoff, csr_src, csr_w, h2h, nullptr,
                                                    nullptr, nxt, nullptr, nullptr, nullptr, nullptr, nullptr);
            cur = nxt;
        }
    }

    // adj = sigmoid(sum(z[row] * z[col]))  on bf16 mirror (now in z0h)
    edge_dot_bf16<<<(N_EDGES + 3) / 4, 256, 0, stream>>>(z0h, srcE, dstE, out_adj, N_EDGES);
}